// Round 1
// baseline (2335.906 us; speedup 1.0000x reference)
//
#include <hip/hip_runtime.h>
#include <cmath>

#define NN 100000
#define NE 800000
#define NL 262144

// ---------------- graph prep ----------------
__global__ void k_deg(const int* __restrict__ dst, const float* __restrict__ w, float* __restrict__ deg) {
  int e = blockIdx.x * 256 + threadIdx.x;
  if (e < NE) atomicAdd(&deg[dst[e]], w[e]);
}
__global__ void k_dinv(float* __restrict__ deg) {
  int n = blockIdx.x * 256 + threadIdx.x;
  if (n < NN) deg[n] = rsqrtf(deg[n] + 1.0f);
}
__global__ void k_enorm(const int* __restrict__ src, const int* __restrict__ dst, const float* __restrict__ w,
                        const float* __restrict__ dinv, float* __restrict__ en) {
  int e = blockIdx.x * 256 + threadIdx.x;
  if (e < NE) en[e] = dinv[src[e]] * w[e] * dinv[dst[e]];
}
__global__ void k_count(const int* __restrict__ dst, int* __restrict__ cnt) {
  int e = blockIdx.x * 256 + threadIdx.x;
  if (e < NE) atomicAdd(&cnt[dst[e]], 1);
}
__global__ void k_scan1(const int* __restrict__ cnt, int* __restrict__ tsum) {
  __shared__ int s[256];
  int t = threadIdx.x;
  int base = blockIdx.x * 1024;
  int acc = 0;
  for (int i = 0; i < 4; i++) { int idx = base + t * 4 + i; if (idx < NN) acc += cnt[idx]; }
  s[t] = acc; __syncthreads();
  for (int o = 128; o > 0; o >>= 1) { if (t < o) s[t] += s[t + o]; __syncthreads(); }
  if (t == 0) tsum[blockIdx.x] = s[0];
}
__global__ void k_scan2(const int* __restrict__ tsum, int* __restrict__ toff, int nt, int* __restrict__ rowptr_end) {
  __shared__ int s[256];
  int t = threadIdx.x;
  int v = (t < nt) ? tsum[t] : 0;
  s[t] = v; __syncthreads();
  for (int o = 1; o < 256; o <<= 1) { int xv = (t >= o) ? s[t - o] : 0; __syncthreads(); s[t] += xv; __syncthreads(); }
  if (t < nt) toff[t] = s[t] - v;
  if (t == 255) *rowptr_end = s[255];
}
__global__ void k_scan3(const int* __restrict__ cnt, const int* __restrict__ toff, int* __restrict__ rowptr) {
  __shared__ int s[256];
  int t = threadIdx.x;
  int base = blockIdx.x * 1024 + t * 4;
  int v[4]; int tot = 0;
  for (int i = 0; i < 4; i++) { int idx = base + i; v[i] = (idx < NN) ? cnt[idx] : 0; tot += v[i]; }
  s[t] = tot; __syncthreads();
  for (int o = 1; o < 256; o <<= 1) { int xv = (t >= o) ? s[t - o] : 0; __syncthreads(); s[t] += xv; __syncthreads(); }
  int excl = s[t] - tot + toff[blockIdx.x];
  for (int i = 0; i < 4; i++) { int idx = base + i; if (idx < NN) rowptr[idx] = excl; excl += v[i]; }
}
__global__ void k_copyi(const int* __restrict__ a, int* __restrict__ b, int n) {
  int i = blockIdx.x * 256 + threadIdx.x; if (i < n) b[i] = a[i];
}
__global__ void k_scatter(const int* __restrict__ src, const int* __restrict__ dst, const float* __restrict__ en,
                          int* __restrict__ nxt, int* __restrict__ esp, float* __restrict__ enp) {
  int e = blockIdx.x * 256 + threadIdx.x;
  if (e < NE) { int d = dst[e]; int p = atomicAdd(&nxt[d], 1); esp[p] = src[e]; enp[p] = en[e]; }
}

// ---------------- GEMMs ----------------
// x [NN,16] @ W [16,256] -> out [NN,256]; 32 rows/block, 256 threads (one col each)
__global__ __launch_bounds__(256) void k_gemm16(const float* __restrict__ x, const float* __restrict__ W,
                                                float* __restrict__ out) {
  __shared__ float xs[32][16];
  int t = threadIdx.x; int row0 = blockIdx.x * 32;
  for (int i = t; i < 512; i += 256) {
    int r = i >> 4, c = i & 15; int row = row0 + r;
    xs[r][c] = (row < NN) ? x[(size_t)row * 16 + c] : 0.f;
  }
  float w[16];
  #pragma unroll
  for (int k = 0; k < 16; k++) w[k] = W[k * 256 + t];
  __syncthreads();
  for (int r = 0; r < 32; r++) {
    int row = row0 + r; if (row >= NN) break;
    float acc = 0.f;
    #pragma unroll
    for (int k = 0; k < 16; k++) acc += xs[r][k] * w[k];
    out[(size_t)row * 256 + t] = acc;
  }
}

// A[NN,256] @ W[256,FOUT] -> C[NN,FOUT]; 64x64 tile, BK=32, 4x4 per thread
template <int FOUT>
__global__ __launch_bounds__(256) void k_gemm(const float* __restrict__ A, const float* __restrict__ W,
                                              float* __restrict__ C) {
  __shared__ __align__(16) float As[32][68]; // [k][r]
  __shared__ __align__(16) float Bs[32][68]; // [k][c]
  int t = threadIdx.x;
  int tx = t & 15, ty = t >> 4;
  int row0 = blockIdx.x * 64, col0 = blockIdx.y * 64;
  float acc[4][4] = {};
  for (int k0 = 0; k0 < 256; k0 += 32) {
    #pragma unroll
    for (int l = 0; l < 2; l++) {
      int idx = t + l * 256;
      int r = idx >> 3, c = (idx & 7) << 2;
      int row = row0 + r;
      float4 v = make_float4(0.f, 0.f, 0.f, 0.f);
      if (row < NN) v = *(const float4*)&A[(size_t)row * 256 + k0 + c];
      As[c + 0][r] = v.x; As[c + 1][r] = v.y; As[c + 2][r] = v.z; As[c + 3][r] = v.w;
    }
    #pragma unroll
    for (int l = 0; l < 2; l++) {
      int idx = t + l * 256;
      int k = idx >> 4, c = (idx & 15) << 2;
      *(float4*)&Bs[k][c] = *(const float4*)&W[(size_t)(k0 + k) * FOUT + col0 + c];
    }
    __syncthreads();
    #pragma unroll
    for (int k = 0; k < 32; k++) {
      float a0 = As[k][ty * 4 + 0], a1 = As[k][ty * 4 + 1], a2 = As[k][ty * 4 + 2], a3 = As[k][ty * 4 + 3];
      float b0 = Bs[k][tx * 4 + 0], b1 = Bs[k][tx * 4 + 1], b2 = Bs[k][tx * 4 + 2], b3 = Bs[k][tx * 4 + 3];
      acc[0][0] += a0 * b0; acc[0][1] += a0 * b1; acc[0][2] += a0 * b2; acc[0][3] += a0 * b3;
      acc[1][0] += a1 * b0; acc[1][1] += a1 * b1; acc[1][2] += a1 * b2; acc[1][3] += a1 * b3;
      acc[2][0] += a2 * b0; acc[2][1] += a2 * b1; acc[2][2] += a2 * b2; acc[2][3] += a2 * b3;
      acc[3][0] += a3 * b0; acc[3][1] += a3 * b1; acc[3][2] += a3 * b2; acc[3][3] += a3 * b3;
    }
    __syncthreads();
  }
  #pragma unroll
  for (int i = 0; i < 4; i++) {
    int row = row0 + ty * 4 + i;
    if (row < NN) {
      float4 v = make_float4(acc[i][0], acc[i][1], acc[i][2], acc[i][3]);
      *(float4*)&C[(size_t)row * FOUT + col0 + tx * 4] = v;
    }
  }
}

// ---------------- aggregation (CSR gather) ----------------
template <int F>
__global__ void k_agg(const float* __restrict__ hW, const int* __restrict__ esp, const float* __restrict__ enp,
                      const int* __restrict__ rowptr, const float* __restrict__ dinv, const float* __restrict__ bias,
                      float* __restrict__ out) {
  int n = blockIdx.x; int f = threadIdx.x;
  float d = dinv[n];
  float acc = hW[(size_t)n * F + f] * (d * d) + bias[f];
  int i1 = rowptr[n + 1];
  for (int i = rowptr[n]; i < i1; ++i)
    acc += enp[i] * hW[(size_t)esp[i] * F + f];
  out[(size_t)n * F + f] = acc;
}

// ---------------- batchnorm ----------------
__global__ void k_bnstats(const float* __restrict__ h, float* __restrict__ sums, float* __restrict__ sqs) {
  int f = threadIdx.x;
  size_t r0 = (size_t)blockIdx.x * 256;
  float s = 0.f, q = 0.f;
  for (int i = 0; i < 256; i++) {
    size_t r = r0 + i; if (r >= NN) break;
    float v = h[r * 256 + f]; s += v; q += v * v;
  }
  atomicAdd(&sums[f], s); atomicAdd(&sqs[f], q);
}
__global__ void k_bnfinal(const float* __restrict__ sums, const float* __restrict__ sqs,
                          const float* __restrict__ g, const float* __restrict__ be,
                          float* __restrict__ scale, float* __restrict__ shift) {
  int f = threadIdx.x;
  float m = sums[f] * (1.f / NN);
  float v = sqs[f] * (1.f / NN) - m * m;
  float sc = g[f] * rsqrtf(v + 1e-5f);
  scale[f] = sc; shift[f] = be[f] - m * sc;
}
__global__ void k_bnrelu(float* __restrict__ h, const float* __restrict__ scale, const float* __restrict__ shift) {
  size_t i = ((size_t)blockIdx.x * 256 + threadIdx.x) * 4;
  float4 v = *(float4*)&h[i];
  int f = (int)(i & 255);
  v.x = fmaxf(v.x * scale[f + 0] + shift[f + 0], 0.f);
  v.y = fmaxf(v.y * scale[f + 1] + shift[f + 1], 0.f);
  v.z = fmaxf(v.z * scale[f + 2] + shift[f + 2], 0.f);
  v.w = fmaxf(v.w * scale[f + 3] + shift[f + 3], 0.f);
  *(float4*)&h[i] = v;
}

// ---------------- fused decoder ----------------
__global__ __launch_bounds__(256) void k_decoder(
    const float* __restrict__ z, const int* __restrict__ l0, const int* __restrict__ l1,
    const float* __restrict__ D1W, const float* __restrict__ D1b,
    const float* __restrict__ D2W, const float* __restrict__ D2b,
    const float* __restrict__ D3W, const float* __restrict__ D3b,
    float* __restrict__ out) {
  __shared__ float smem[64 * 257 + 64 * 132];
  float* in_lds = smem;           // [64][257] input (later q1 [64][129])
  float* w_lds = smem + 64 * 257; // [64][132]
  __shared__ int ei[2][64];
  int t = threadIdx.x;
  int base = blockIdx.x * 64;
  if (t < 64) ei[0][t] = l0[base + t];
  else if (t < 128) ei[1][t - 64] = l1[base + t - 64];
  __syncthreads();
  // phase A: gather [z[e0], z[e1]] rows -> in_lds
  for (int i = t; i < 64 * 64; i += 256) {
    int e = i >> 6, c4 = i & 63;
    int node = (c4 < 32) ? ei[0][e] : ei[1][e];
    int kb = (c4 & 31) << 2;
    float4 v = *(const float4*)&z[(size_t)node * 128 + kb];
    float* dp = &in_lds[e * 257 + ((c4 < 32) ? 0 : 128) + kb];
    dp[0] = v.x; dp[1] = v.y; dp[2] = v.z; dp[3] = v.w;
  }
  int eg = t >> 5, jg = t & 31;
  // phase B: q1 = relu(in @ D1W + b1)
  float acc[8][4] = {};
  for (int k0 = 0; k0 < 256; k0 += 64) {
    __syncthreads();
    for (int i = t; i < 64 * 32; i += 256) {
      int kk = i >> 5, c4 = (i & 31) << 2;
      *(float4*)&w_lds[kk * 132 + c4] = *(const float4*)&D1W[(size_t)(k0 + kk) * 128 + c4];
    }
    __syncthreads();
    #pragma unroll 16
    for (int kk = 0; kk < 64; kk++) {
      float a[8], wv[4];
      #pragma unroll
      for (int i = 0; i < 8; i++) a[i] = in_lds[(eg * 8 + i) * 257 + k0 + kk];
      #pragma unroll
      for (int j = 0; j < 4; j++) wv[j] = w_lds[kk * 132 + jg + 32 * j];
      #pragma unroll
      for (int i = 0; i < 8; i++)
        #pragma unroll
        for (int j = 0; j < 4; j++) acc[i][j] += a[i] * wv[j];
    }
  }
  __syncthreads();
  float b1r[4];
  #pragma unroll
  for (int j = 0; j < 4; j++) b1r[j] = D1b[jg + 32 * j];
  #pragma unroll
  for (int i = 0; i < 8; i++)
    #pragma unroll
    for (int j = 0; j < 4; j++)
      in_lds[(eg * 8 + i) * 129 + jg + 32 * j] = fmaxf(acc[i][j] + b1r[j], 0.f);
  // phase C: q2 = relu(q1 @ D2W + b2)
  float acc2[8][4] = {};
  for (int k0 = 0; k0 < 128; k0 += 64) {
    __syncthreads();
    for (int i = t; i < 64 * 32; i += 256) {
      int kk = i >> 5, c4 = (i & 31) << 2;
      *(float4*)&w_lds[kk * 132 + c4] = *(const float4*)&D2W[(size_t)(k0 + kk) * 128 + c4];
    }
    __syncthreads();
    #pragma unroll 16
    for (int kk = 0; kk < 64; kk++) {
      float a[8], wv[4];
      #pragma unroll
      for (int i = 0; i < 8; i++) a[i] = in_lds[(eg * 8 + i) * 129 + k0 + kk];
      #pragma unroll
      for (int j = 0; j < 4; j++) wv[j] = w_lds[kk * 132 + jg + 32 * j];
      #pragma unroll
      for (int i = 0; i < 8; i++)
        #pragma unroll
        for (int j = 0; j < 4; j++) acc2[i][j] += a[i] * wv[j];
    }
  }
  // phase D: p = sigmoid(q2 . D3W + b)
  float b2r[4], w3r[4];
  #pragma unroll
  for (int j = 0; j < 4; j++) { b2r[j] = D2b[jg + 32 * j]; w3r[j] = D3W[jg + 32 * j]; }
  float d3b = D3b[0];
  #pragma unroll
  for (int i = 0; i < 8; i++) {
    float s = 0.f;
    #pragma unroll
    for (int j = 0; j < 4; j++) s += fmaxf(acc2[i][j] + b2r[j], 0.f) * w3r[j];
    #pragma unroll
    for (int m = 1; m < 32; m <<= 1) s += __shfl_xor(s, m);
    if (jg == 0) out[base + eg * 8 + i] = 1.f / (1.f + expf(-(s + d3b)));
  }
}

// ---------------- host ----------------
extern "C" void kernel_launch(void* const* d_in, const int* in_sizes, int n_in,
                              void* d_out, int out_size, void* d_ws, size_t ws_size,
                              hipStream_t stream) {
  const float* x = (const float*)d_in[0];
  const int* ei = (const int*)d_in[1];
  const int* esrc = ei; const int* edst = ei + NE;
  const float* ew = (const float*)d_in[2];
  const int* eli = (const int*)d_in[3];
  const int* l0 = eli; const int* l1 = eli + NL;
  const float* W1 = (const float*)d_in[4],  *b1 = (const float*)d_in[5];
  const float* g1 = (const float*)d_in[6],  *be1 = (const float*)d_in[7];
  const float* W2 = (const float*)d_in[8],  *b2 = (const float*)d_in[9];
  const float* g2 = (const float*)d_in[10], *be2 = (const float*)d_in[11];
  const float* W3 = (const float*)d_in[12], *b3 = (const float*)d_in[13];
  const float* g3 = (const float*)d_in[14], *be3 = (const float*)d_in[15];
  const float* W4 = (const float*)d_in[16], *b4 = (const float*)d_in[17];
  const float* D1W = (const float*)d_in[18], *D1b = (const float*)d_in[19];
  const float* D2W = (const float*)d_in[20], *D2b = (const float*)d_in[21];
  const float* D3W = (const float*)d_in[22], *D3b = (const float*)d_in[23];
  float* out = (float*)d_out;

  float* wf = (float*)d_ws;
  size_t off = 0;
  auto A = [&](size_t n) { float* p = wf + off; off += (n + 63) & ~(size_t)63; return p; };
  float* dinv = A(NN);
  float* en = A(NE);
  float* enp = A(NE);
  float* sums = A(256);
  float* sqs = A(256);   // contiguous with sums
  float* scale = A(256);
  float* shift = A(256);
  float* buf0 = A((size_t)NN * 256);
  float* buf1 = A((size_t)NN * 256);
  int* cnt = (int*)A(NN);
  int* rowptr = (int*)A(NN + 1);
  int* nxt = (int*)A(NN);
  int* esp = (int*)A(NE);
  int* tsum = (int*)A(256);
  int* toff = (int*)A(256);

  const int EB = (NE + 255) / 256;     // 3125
  const int NB = (NN + 255) / 256;     // 391
  const int ST = (NN + 1023) / 1024;   // 98

  // graph prep
  hipMemsetAsync(dinv, 0, NN * sizeof(float), stream);
  hipMemsetAsync(cnt, 0, NN * sizeof(int), stream);
  k_deg<<<EB, 256, 0, stream>>>(edst, ew, dinv);
  k_dinv<<<NB, 256, 0, stream>>>(dinv);
  k_enorm<<<EB, 256, 0, stream>>>(esrc, edst, ew, dinv, en);
  k_count<<<EB, 256, 0, stream>>>(edst, cnt);
  k_scan1<<<ST, 256, 0, stream>>>(cnt, tsum);
  k_scan2<<<1, 256, 0, stream>>>(tsum, toff, ST, rowptr + NN);
  k_scan3<<<ST, 256, 0, stream>>>(cnt, toff, rowptr);
  k_copyi<<<NB, 256, 0, stream>>>(rowptr, nxt, NN);
  k_scatter<<<EB, 256, 0, stream>>>(esrc, edst, en, nxt, esp, enp);

  dim3 g256((NN + 63) / 64, 4), g128((NN + 63) / 64, 2);

  // layer 1
  k_gemm16<<<(NN + 31) / 32, 256, 0, stream>>>(x, W1, buf0);
  k_agg<256><<<NN, 256, 0, stream>>>(buf0, esp, enp, rowptr, dinv, b1, buf1);
  hipMemsetAsync(sums, 0, 512 * sizeof(float), stream);
  k_bnstats<<<NB, 256, 0, stream>>>(buf1, sums, sqs);
  k_bnfinal<<<1, 256, 0, stream>>>(sums, sqs, g1, be1, scale, shift);
  k_bnrelu<<<(int)(((size_t)NN * 256 / 4 + 255) / 256), 256, 0, stream>>>(buf1, scale, shift);
  // layer 2
  k_gemm<256><<<g256, 256, 0, stream>>>(buf1, W2, buf0);
  k_agg<256><<<NN, 256, 0, stream>>>(buf0, esp, enp, rowptr, dinv, b2, buf1);
  hipMemsetAsync(sums, 0, 512 * sizeof(float), stream);
  k_bnstats<<<NB, 256, 0, stream>>>(buf1, sums, sqs);
  k_bnfinal<<<1, 256, 0, stream>>>(sums, sqs, g2, be2, scale, shift);
  k_bnrelu<<<(int)(((size_t)NN * 256 / 4 + 255) / 256), 256, 0, stream>>>(buf1, scale, shift);
  // layer 3
  k_gemm<256><<<g256, 256, 0, stream>>>(buf1, W3, buf0);
  k_agg<256><<<NN, 256, 0, stream>>>(buf0, esp, enp, rowptr, dinv, b3, buf1);
  hipMemsetAsync(sums, 0, 512 * sizeof(float), stream);
  k_bnstats<<<NB, 256, 0, stream>>>(buf1, sums, sqs);
  k_bnfinal<<<1, 256, 0, stream>>>(sums, sqs, g3, be3, scale, shift);
  k_bnrelu<<<(int)(((size_t)NN * 256 / 4 + 255) / 256), 256, 0, stream>>>(buf1, scale, shift);
  // layer 4 (no BN/relu)
  k_gemm<128><<<g128, 256, 0, stream>>>(buf1, W4, buf0);
  k_agg<128><<<NN, 128, 0, stream>>>(buf0, esp, enp, rowptr, dinv, b4, buf1);
  // decoder
  k_decoder<<<NL / 64, 256, 0, stream>>>(buf1, l0, l1, D1W, D1b, D2W, D2b, D3W, D3b, out);
}

// Round 2
// 1729.933 us; speedup vs baseline: 1.3503x; 1.3503x over previous
//
#include <hip/hip_runtime.h>
#include <cmath>

#define NN 100000
#define NE 800000
#define NL 262144

typedef __attribute__((ext_vector_type(8))) short bf16x8;
typedef __attribute__((ext_vector_type(4))) float f32x4;

__device__ __forceinline__ unsigned short f2bf(float f) {
  unsigned int u = __builtin_bit_cast(unsigned int, f);
  u = (u + 0x7FFF + ((u >> 16) & 1)) >> 16;
  return (unsigned short)u;
}

// ---------------- graph prep ----------------
__global__ void k_deg(const int* __restrict__ dst, const float* __restrict__ w, float* __restrict__ deg) {
  int e = blockIdx.x * 256 + threadIdx.x;
  if (e < NE) atomicAdd(&deg[dst[e]], w[e]);
}
__global__ void k_dinv(float* __restrict__ deg) {
  int n = blockIdx.x * 256 + threadIdx.x;
  if (n < NN) deg[n] = rsqrtf(deg[n] + 1.0f);
}
__global__ void k_enorm(const int* __restrict__ src, const int* __restrict__ dst, const float* __restrict__ w,
                        const float* __restrict__ dinv, float* __restrict__ en) {
  int e = blockIdx.x * 256 + threadIdx.x;
  if (e < NE) en[e] = dinv[src[e]] * w[e] * dinv[dst[e]];
}
__global__ void k_count(const int* __restrict__ dst, int* __restrict__ cnt) {
  int e = blockIdx.x * 256 + threadIdx.x;
  if (e < NE) atomicAdd(&cnt[dst[e]], 1);
}
__global__ void k_scan1(const int* __restrict__ cnt, int* __restrict__ tsum) {
  __shared__ int s[256];
  int t = threadIdx.x;
  int base = blockIdx.x * 1024;
  int acc = 0;
  for (int i = 0; i < 4; i++) { int idx = base + t * 4 + i; if (idx < NN) acc += cnt[idx]; }
  s[t] = acc; __syncthreads();
  for (int o = 128; o > 0; o >>= 1) { if (t < o) s[t] += s[t + o]; __syncthreads(); }
  if (t == 0) tsum[blockIdx.x] = s[0];
}
__global__ void k_scan2(const int* __restrict__ tsum, int* __restrict__ toff, int nt, int* __restrict__ rowptr_end) {
  __shared__ int s[256];
  int t = threadIdx.x;
  int v = (t < nt) ? tsum[t] : 0;
  s[t] = v; __syncthreads();
  for (int o = 1; o < 256; o <<= 1) { int xv = (t >= o) ? s[t - o] : 0; __syncthreads(); s[t] += xv; __syncthreads(); }
  if (t < nt) toff[t] = s[t] - v;
  if (t == 255) *rowptr_end = s[255];
}
__global__ void k_scan3(const int* __restrict__ cnt, const int* __restrict__ toff, int* __restrict__ rowptr) {
  __shared__ int s[256];
  int t = threadIdx.x;
  int base = blockIdx.x * 1024 + t * 4;
  int v[4]; int tot = 0;
  for (int i = 0; i < 4; i++) { int idx = base + i; v[i] = (idx < NN) ? cnt[idx] : 0; tot += v[i]; }
  s[t] = tot; __syncthreads();
  for (int o = 1; o < 256; o <<= 1) { int xv = (t >= o) ? s[t - o] : 0; __syncthreads(); s[t] += xv; __syncthreads(); }
  int excl = s[t] - tot + toff[blockIdx.x];
  for (int i = 0; i < 4; i++) { int idx = base + i; if (idx < NN) rowptr[idx] = excl; excl += v[i]; }
}
__global__ void k_copyi(const int* __restrict__ a, int* __restrict__ b, int n) {
  int i = blockIdx.x * 256 + threadIdx.x; if (i < n) b[i] = a[i];
}
__global__ void k_scatter(const int* __restrict__ src, const int* __restrict__ dst, const float* __restrict__ en,
                          int* __restrict__ nxt, int* __restrict__ esp, float* __restrict__ enp) {
  int e = blockIdx.x * 256 + threadIdx.x;
  if (e < NE) { int d = dst[e]; int p = atomicAdd(&nxt[d], 1); esp[p] = src[e]; enp[p] = en[e]; }
}

// ---------------- GEMMs (encoder, fp32) ----------------
__global__ __launch_bounds__(256) void k_gemm16(const float* __restrict__ x, const float* __restrict__ W,
                                                float* __restrict__ out) {
  __shared__ float xs[32][16];
  int t = threadIdx.x; int row0 = blockIdx.x * 32;
  for (int i = t; i < 512; i += 256) {
    int r = i >> 4, c = i & 15; int row = row0 + r;
    xs[r][c] = (row < NN) ? x[(size_t)row * 16 + c] : 0.f;
  }
  float w[16];
  #pragma unroll
  for (int k = 0; k < 16; k++) w[k] = W[k * 256 + t];
  __syncthreads();
  for (int r = 0; r < 32; r++) {
    int row = row0 + r; if (row >= NN) break;
    float acc = 0.f;
    #pragma unroll
    for (int k = 0; k < 16; k++) acc += xs[r][k] * w[k];
    out[(size_t)row * 256 + t] = acc;
  }
}

template <int FOUT>
__global__ __launch_bounds__(256) void k_gemm(const float* __restrict__ A, const float* __restrict__ W,
                                              float* __restrict__ C) {
  __shared__ __align__(16) float As[32][68];
  __shared__ __align__(16) float Bs[32][68];
  int t = threadIdx.x;
  int tx = t & 15, ty = t >> 4;
  int row0 = blockIdx.x * 64, col0 = blockIdx.y * 64;
  float acc[4][4] = {};
  for (int k0 = 0; k0 < 256; k0 += 32) {
    #pragma unroll
    for (int l = 0; l < 2; l++) {
      int idx = t + l * 256;
      int r = idx >> 3, c = (idx & 7) << 2;
      int row = row0 + r;
      float4 v = make_float4(0.f, 0.f, 0.f, 0.f);
      if (row < NN) v = *(const float4*)&A[(size_t)row * 256 + k0 + c];
      As[c + 0][r] = v.x; As[c + 1][r] = v.y; As[c + 2][r] = v.z; As[c + 3][r] = v.w;
    }
    #pragma unroll
    for (int l = 0; l < 2; l++) {
      int idx = t + l * 256;
      int k = idx >> 4, c = (idx & 15) << 2;
      *(float4*)&Bs[k][c] = *(const float4*)&W[(size_t)(k0 + k) * FOUT + col0 + c];
    }
    __syncthreads();
    #pragma unroll
    for (int k = 0; k < 32; k++) {
      float a0 = As[k][ty * 4 + 0], a1 = As[k][ty * 4 + 1], a2 = As[k][ty * 4 + 2], a3 = As[k][ty * 4 + 3];
      float b0 = Bs[k][tx * 4 + 0], b1 = Bs[k][tx * 4 + 1], b2 = Bs[k][tx * 4 + 2], b3 = Bs[k][tx * 4 + 3];
      acc[0][0] += a0 * b0; acc[0][1] += a0 * b1; acc[0][2] += a0 * b2; acc[0][3] += a0 * b3;
      acc[1][0] += a1 * b0; acc[1][1] += a1 * b1; acc[1][2] += a1 * b2; acc[1][3] += a1 * b3;
      acc[2][0] += a2 * b0; acc[2][1] += a2 * b1; acc[2][2] += a2 * b2; acc[2][3] += a2 * b3;
      acc[3][0] += a3 * b0; acc[3][1] += a3 * b1; acc[3][2] += a3 * b2; acc[3][3] += a3 * b3;
    }
    __syncthreads();
  }
  #pragma unroll
  for (int i = 0; i < 4; i++) {
    int row = row0 + ty * 4 + i;
    if (row < NN) {
      float4 v = make_float4(acc[i][0], acc[i][1], acc[i][2], acc[i][3]);
      *(float4*)&C[(size_t)row * FOUT + col0 + tx * 4] = v;
    }
  }
}

// ---------------- aggregation (CSR gather) ----------------
template <int F>
__global__ void k_agg(const float* __restrict__ hW, const int* __restrict__ esp, const float* __restrict__ enp,
                      const int* __restrict__ rowptr, const float* __restrict__ dinv, const float* __restrict__ bias,
                      float* __restrict__ out) {
  int n = blockIdx.x; int f = threadIdx.x;
  float d = dinv[n];
  float acc = hW[(size_t)n * F + f] * (d * d) + bias[f];
  int i1 = rowptr[n + 1];
  for (int i = rowptr[n]; i < i1; ++i)
    acc += enp[i] * hW[(size_t)esp[i] * F + f];
  out[(size_t)n * F + f] = acc;
}

// ---------------- batchnorm ----------------
__global__ void k_bnstats(const float* __restrict__ h, float* __restrict__ sums, float* __restrict__ sqs) {
  int f = threadIdx.x;
  size_t r0 = (size_t)blockIdx.x * 256;
  float s = 0.f, q = 0.f;
  for (int i = 0; i < 256; i++) {
    size_t r = r0 + i; if (r >= NN) break;
    float v = h[r * 256 + f]; s += v; q += v * v;
  }
  atomicAdd(&sums[f], s); atomicAdd(&sqs[f], q);
}
__global__ void k_bnfinal(const float* __restrict__ sums, const float* __restrict__ sqs,
                          const float* __restrict__ g, const float* __restrict__ be,
                          float* __restrict__ scale, float* __restrict__ shift) {
  int f = threadIdx.x;
  float m = sums[f] * (1.f / NN);
  float v = sqs[f] * (1.f / NN) - m * m;
  float sc = g[f] * rsqrtf(v + 1e-5f);
  scale[f] = sc; shift[f] = be[f] - m * sc;
}
__global__ void k_bnrelu(float* __restrict__ h, const float* __restrict__ scale, const float* __restrict__ shift) {
  size_t i = ((size_t)blockIdx.x * 256 + threadIdx.x) * 4;
  float4 v = *(float4*)&h[i];
  int f = (int)(i & 255);
  v.x = fmaxf(v.x * scale[f + 0] + shift[f + 0], 0.f);
  v.y = fmaxf(v.y * scale[f + 1] + shift[f + 1], 0.f);
  v.z = fmaxf(v.z * scale[f + 2] + shift[f + 2], 0.f);
  v.w = fmaxf(v.w * scale[f + 3] + shift[f + 3], 0.f);
  *(float4*)&h[i] = v;
}

// ---------------- bf16 conversions for decoder ----------------
__global__ void k_cvt_z(const float* __restrict__ z, unsigned short* __restrict__ zbf) {
  size_t i = ((size_t)blockIdx.x * 256 + threadIdx.x) * 4;   // NN*128 divisible by 1024
  float4 v = *(const float4*)(z + i);
  ushort4 o;
  o.x = f2bf(v.x); o.y = f2bf(v.y); o.z = f2bf(v.z); o.w = f2bf(v.w);
  *(ushort4*)(zbf + i) = o;
}
// D1W [256][128] -> W1t [128][256] bf16
__global__ void k_cvt_w1(const float* __restrict__ W, unsigned short* __restrict__ Wt) {
  int id = blockIdx.x * 256 + threadIdx.x;   // 32768
  int k = id & 255, n = id >> 8;
  Wt[n * 256 + k] = f2bf(W[k * 128 + n]);
}
// D2W [128][128] -> W2t [128][128] bf16
__global__ void k_cvt_w2(const float* __restrict__ W, unsigned short* __restrict__ Wt) {
  int id = blockIdx.x * 256 + threadIdx.x;   // 16384
  int k = id & 127, n = id >> 7;
  Wt[n * 128 + k] = f2bf(W[k * 128 + n]);
}

// ---------------- fused decoder (bf16 MFMA) ----------------
// 128 edges/block, 256 threads = 4 waves; wave w owns edges [w*32, w*32+32), all 128 cols.
__global__ __launch_bounds__(256) void k_decoder2(
    const unsigned short* __restrict__ zbf, const int* __restrict__ l0, const int* __restrict__ l1,
    const unsigned short* __restrict__ W1t, const float* __restrict__ D1b,
    const unsigned short* __restrict__ W2t, const float* __restrict__ D2b,
    const float* __restrict__ D3W, const float* __restrict__ D3b,
    float* __restrict__ out) {
  __shared__ unsigned short S[128 * 264];  // Ain [128][256] stride 264 (132 dw -> uniform 8 dw/bank on b128)
  __shared__ int ei0[128], ei1[128];
  const int t = threadIdx.x;
  const int base = blockIdx.x * 128;
  if (t < 128) ei0[t] = l0[base + t];
  else ei1[t - 128] = l1[base + t - 128];
  __syncthreads();
  // gather: thread t -> edge e=t>>1, half h=t&1; copy 128 bf16 = 16x uint4
  {
    int e = t >> 1, h = t & 1;
    int node = h ? ei1[e] : ei0[e];
    const uint4* src = (const uint4*)(zbf + (size_t)node * 128);
    uint4* dst = (uint4*)(S + e * 264 + h * 128);
    #pragma unroll
    for (int i = 0; i < 16; i++) dst[i] = src[i];
  }
  __syncthreads();
  const int lane = t & 63, w = t >> 6, fr = lane & 15, fq = lane >> 4;
  float b1v[8];
  #pragma unroll
  for (int j = 0; j < 8; j++) b1v[j] = D1b[j * 16 + fr];
  // ---- layer 1: q1[128][128] = relu(Ain[128][256] @ D1W) ----
  f32x4 acc[2][8] = {};
  #pragma unroll
  for (int s = 0; s < 8; s++) {
    bf16x8 a0 = *(const bf16x8*)(S + (w * 32 + fr) * 264 + s * 32 + fq * 8);
    bf16x8 a1 = *(const bf16x8*)(S + (w * 32 + 16 + fr) * 264 + s * 32 + fq * 8);
    bf16x8 bw[8];
    #pragma unroll
    for (int j = 0; j < 8; j++)
      bw[j] = *(const bf16x8*)(W1t + (size_t)(j * 16 + fr) * 256 + s * 32 + fq * 8);
    #pragma unroll
    for (int j = 0; j < 8; j++) {
      acc[0][j] = __builtin_amdgcn_mfma_f32_16x16x32_bf16(a0, bw[j], acc[0][j], 0, 0, 0);
      acc[1][j] = __builtin_amdgcn_mfma_f32_16x16x32_bf16(a1, bw[j], acc[1][j], 0, 0, 0);
    }
  }
  __syncthreads();  // everyone done reading Ain before q1 overwrites it
  // q1 -> bf16 into S (stride 136 ushorts)
  #pragma unroll
  for (int f = 0; f < 2; f++)
    #pragma unroll
    for (int j = 0; j < 8; j++)
      #pragma unroll
      for (int r = 0; r < 4; r++) {
        int row = w * 32 + f * 16 + fq * 4 + r;
        S[row * 136 + j * 16 + fr] = f2bf(fmaxf(acc[f][j][r] + b1v[j], 0.f));
      }
  __syncthreads();
  // ---- layer 2: q2 = relu(q1 @ D2W) ----
  f32x4 acc2[2][8] = {};
  #pragma unroll
  for (int s = 0; s < 4; s++) {
    bf16x8 a0 = *(const bf16x8*)(S + (w * 32 + fr) * 136 + s * 32 + fq * 8);
    bf16x8 a1 = *(const bf16x8*)(S + (w * 32 + 16 + fr) * 136 + s * 32 + fq * 8);
    bf16x8 bw[8];
    #pragma unroll
    for (int j = 0; j < 8; j++)
      bw[j] = *(const bf16x8*)(W2t + (size_t)(j * 16 + fr) * 128 + s * 32 + fq * 8);
    #pragma unroll
    for (int j = 0; j < 8; j++) {
      acc2[0][j] = __builtin_amdgcn_mfma_f32_16x16x32_bf16(a0, bw[j], acc2[0][j], 0, 0, 0);
      acc2[1][j] = __builtin_amdgcn_mfma_f32_16x16x32_bf16(a1, bw[j], acc2[1][j], 0, 0, 0);
    }
  }
  // ---- layer 3: p = sigmoid(relu(q2) . D3W + b) ----
  float b2v[8], w3v[8];
  #pragma unroll
  for (int j = 0; j < 8; j++) { b2v[j] = D2b[j * 16 + fr]; w3v[j] = D3W[j * 16 + fr]; }
  float d3b = D3b[0];
  #pragma unroll
  for (int f = 0; f < 2; f++) {
    float p[4] = {0.f, 0.f, 0.f, 0.f};
    #pragma unroll
    for (int j = 0; j < 8; j++)
      #pragma unroll
      for (int r = 0; r < 4; r++)
        p[r] += fmaxf(acc2[f][j][r] + b2v[j], 0.f) * w3v[j];
    #pragma unroll
    for (int r = 0; r < 4; r++) {
      p[r] += __shfl_xor(p[r], 1);
      p[r] += __shfl_xor(p[r], 2);
      p[r] += __shfl_xor(p[r], 4);
      p[r] += __shfl_xor(p[r], 8);
      if (fr == 0) out[base + w * 32 + f * 16 + fq * 4 + r] = 1.f / (1.f + expf(-(p[r] + d3b)));
    }
  }
}

// ---------------- host ----------------
extern "C" void kernel_launch(void* const* d_in, const int* in_sizes, int n_in,
                              void* d_out, int out_size, void* d_ws, size_t ws_size,
                              hipStream_t stream) {
  const float* x = (const float*)d_in[0];
  const int* ei = (const int*)d_in[1];
  const int* esrc = ei; const int* edst = ei + NE;
  const float* ew = (const float*)d_in[2];
  const int* eli = (const int*)d_in[3];
  const int* l0 = eli; const int* l1 = eli + NL;
  const float* W1 = (const float*)d_in[4],  *b1 = (const float*)d_in[5];
  const float* g1 = (const float*)d_in[6],  *be1 = (const float*)d_in[7];
  const float* W2 = (const float*)d_in[8],  *b2 = (const float*)d_in[9];
  const float* g2 = (const float*)d_in[10], *be2 = (const float*)d_in[11];
  const float* W3 = (const float*)d_in[12], *b3 = (const float*)d_in[13];
  const float* g3 = (const float*)d_in[14], *be3 = (const float*)d_in[15];
  const float* W4 = (const float*)d_in[16], *b4 = (const float*)d_in[17];
  const float* D1W = (const float*)d_in[18], *D1b = (const float*)d_in[19];
  const float* D2W = (const float*)d_in[20], *D2b = (const float*)d_in[21];
  const float* D3W = (const float*)d_in[22], *D3b = (const float*)d_in[23];
  float* out = (float*)d_out;

  float* wf = (float*)d_ws;
  size_t off = 0;
  auto A = [&](size_t n) { float* p = wf + off; off += (n + 63) & ~(size_t)63; return p; };
  float* dinv = A(NN);
  float* en = A(NE);
  float* enp = A(NE);
  float* sums = A(256);
  float* sqs = A(256);
  float* scale = A(256);
  float* shift = A(256);
  float* buf0 = A((size_t)NN * 256);
  float* buf1 = A((size_t)NN * 256);
  int* cnt = (int*)A(NN);
  int* rowptr = (int*)A(NN + 1);
  int* nxt = (int*)A(NN);
  int* esp = (int*)A(NE);
  int* tsum = (int*)A(256);
  int* toff = (int*)A(256);

  // bf16 decoder inputs carved out of buf0 (free after layer-4 agg)
  unsigned short* zbf = (unsigned short*)buf0;
  unsigned short* w1t = zbf + (size_t)NN * 128;
  unsigned short* w2t = w1t + 128 * 256;

  const int EB = (NE + 255) / 256;
  const int NB = (NN + 255) / 256;
  const int ST = (NN + 1023) / 1024;

  // graph prep
  hipMemsetAsync(dinv, 0, NN * sizeof(float), stream);
  hipMemsetAsync(cnt, 0, NN * sizeof(int), stream);
  k_deg<<<EB, 256, 0, stream>>>(edst, ew, dinv);
  k_dinv<<<NB, 256, 0, stream>>>(dinv);
  k_enorm<<<EB, 256, 0, stream>>>(esrc, edst, ew, dinv, en);
  k_count<<<EB, 256, 0, stream>>>(edst, cnt);
  k_scan1<<<ST, 256, 0, stream>>>(cnt, tsum);
  k_scan2<<<1, 256, 0, stream>>>(tsum, toff, ST, rowptr + NN);
  k_scan3<<<ST, 256, 0, stream>>>(cnt, toff, rowptr);
  k_copyi<<<NB, 256, 0, stream>>>(rowptr, nxt, NN);
  k_scatter<<<EB, 256, 0, stream>>>(esrc, edst, en, nxt, esp, enp);

  dim3 g256((NN + 63) / 64, 4), g128((NN + 63) / 64, 2);

  // layer 1
  k_gemm16<<<(NN + 31) / 32, 256, 0, stream>>>(x, W1, buf0);
  k_agg<256><<<NN, 256, 0, stream>>>(buf0, esp, enp, rowptr, dinv, b1, buf1);
  hipMemsetAsync(sums, 0, 512 * sizeof(float), stream);
  k_bnstats<<<NB, 256, 0, stream>>>(buf1, sums, sqs);
  k_bnfinal<<<1, 256, 0, stream>>>(sums, sqs, g1, be1, scale, shift);
  k_bnrelu<<<(int)(((size_t)NN * 256 / 4 + 255) / 256), 256, 0, stream>>>(buf1, scale, shift);
  // layer 2
  k_gemm<256><<<g256, 256, 0, stream>>>(buf1, W2, buf0);
  k_agg<256><<<NN, 256, 0, stream>>>(buf0, esp, enp, rowptr, dinv, b2, buf1);
  hipMemsetAsync(sums, 0, 512 * sizeof(float), stream);
  k_bnstats<<<NB, 256, 0, stream>>>(buf1, sums, sqs);
  k_bnfinal<<<1, 256, 0, stream>>>(sums, sqs, g2, be2, scale, shift);
  k_bnrelu<<<(int)(((size_t)NN * 256 / 4 + 255) / 256), 256, 0, stream>>>(buf1, scale, shift);
  // layer 3
  k_gemm<256><<<g256, 256, 0, stream>>>(buf1, W3, buf0);
  k_agg<256><<<NN, 256, 0, stream>>>(buf0, esp, enp, rowptr, dinv, b3, buf1);
  hipMemsetAsync(sums, 0, 512 * sizeof(float), stream);
  k_bnstats<<<NB, 256, 0, stream>>>(buf1, sums, sqs);
  k_bnfinal<<<1, 256, 0, stream>>>(sums, sqs, g3, be3, scale, shift);
  k_bnrelu<<<(int)(((size_t)NN * 256 / 4 + 255) / 256), 256, 0, stream>>>(buf1, scale, shift);
  // layer 4 (no BN/relu)
  k_gemm<128><<<g128, 256, 0, stream>>>(buf1, W4, buf0);
  k_agg<128><<<NN, 128, 0, stream>>>(buf0, esp, enp, rowptr, dinv, b4, buf1);

  // decoder (bf16 MFMA)
  k_cvt_z<<<(int)((size_t)NN * 128 / 1024), 256, 0, stream>>>(buf1, zbf);
  k_cvt_w1<<<128, 256, 0, stream>>>(D1W, w1t);
  k_cvt_w2<<<64, 256, 0, stream>>>(D2W, w2t);
  k_decoder2<<<NL / 128, 256, 0, stream>>>(zbf, l0, l1, w1t, D1b, w2t, D2b, D3W, D3b, out);
}

// Round 3
// 982.015 us; speedup vs baseline: 2.3787x; 1.7616x over previous
//
#include <hip/hip_runtime.h>
#include <cmath>

#define NN 100000
#define NE 800000
#define NL 262144

typedef __attribute__((ext_vector_type(8))) short bf16x8;
typedef __attribute__((ext_vector_type(4))) float f32x4;

__device__ __forceinline__ unsigned short f2bf(float f) {
  unsigned int u = __builtin_bit_cast(unsigned int, f);
  u = (u + 0x7FFF + ((u >> 16) & 1)) >> 16;
  return (unsigned short)u;
}
__device__ __forceinline__ float bf2f(unsigned short u) {
  return __builtin_bit_cast(float, (unsigned int)u << 16);
}

// ---------------- graph prep ----------------
__global__ void k_deg(const int* __restrict__ dst, const float* __restrict__ w, float* __restrict__ deg) {
  int e = blockIdx.x * 256 + threadIdx.x;
  if (e < NE) atomicAdd(&deg[dst[e]], w[e]);
}
__global__ void k_dinv(float* __restrict__ deg) {
  int n = blockIdx.x * 256 + threadIdx.x;
  if (n < NN) deg[n] = rsqrtf(deg[n] + 1.0f);
}
__global__ void k_enorm(const int* __restrict__ src, const int* __restrict__ dst, const float* __restrict__ w,
                        const float* __restrict__ dinv, float* __restrict__ en) {
  int e = blockIdx.x * 256 + threadIdx.x;
  if (e < NE) en[e] = dinv[src[e]] * w[e] * dinv[dst[e]];
}
__global__ void k_count(const int* __restrict__ dst, int* __restrict__ cnt) {
  int e = blockIdx.x * 256 + threadIdx.x;
  if (e < NE) atomicAdd(&cnt[dst[e]], 1);
}
__global__ void k_scan1(const int* __restrict__ cnt, int* __restrict__ tsum) {
  __shared__ int s[256];
  int t = threadIdx.x;
  int base = blockIdx.x * 1024;
  int acc = 0;
  for (int i = 0; i < 4; i++) { int idx = base + t * 4 + i; if (idx < NN) acc += cnt[idx]; }
  s[t] = acc; __syncthreads();
  for (int o = 128; o > 0; o >>= 1) { if (t < o) s[t] += s[t + o]; __syncthreads(); }
  if (t == 0) tsum[blockIdx.x] = s[0];
}
__global__ void k_scan2(const int* __restrict__ tsum, int* __restrict__ toff, int nt, int* __restrict__ rowptr_end) {
  __shared__ int s[256];
  int t = threadIdx.x;
  int v = (t < nt) ? tsum[t] : 0;
  s[t] = v; __syncthreads();
  for (int o = 1; o < 256; o <<= 1) { int xv = (t >= o) ? s[t - o] : 0; __syncthreads(); s[t] += xv; __syncthreads(); }
  if (t < nt) toff[t] = s[t] - v;
  if (t == 255) *rowptr_end = s[255];
}
__global__ void k_scan3(const int* __restrict__ cnt, const int* __restrict__ toff, int* __restrict__ rowptr) {
  __shared__ int s[256];
  int t = threadIdx.x;
  int base = blockIdx.x * 1024 + t * 4;
  int v[4]; int tot = 0;
  for (int i = 0; i < 4; i++) { int idx = base + i; v[i] = (idx < NN) ? cnt[idx] : 0; tot += v[i]; }
  s[t] = tot; __syncthreads();
  for (int o = 1; o < 256; o <<= 1) { int xv = (t >= o) ? s[t - o] : 0; __syncthreads(); s[t] += xv; __syncthreads(); }
  int excl = s[t] - tot + toff[blockIdx.x];
  for (int i = 0; i < 4; i++) { int idx = base + i; if (idx < NN) rowptr[idx] = excl; excl += v[i]; }
}
__global__ void k_copyi(const int* __restrict__ a, int* __restrict__ b, int n) {
  int i = blockIdx.x * 256 + threadIdx.x; if (i < n) b[i] = a[i];
}
__global__ void k_scatter(const int* __restrict__ src, const int* __restrict__ dst, const float* __restrict__ en,
                          int* __restrict__ nxt, int* __restrict__ esp, float* __restrict__ enp) {
  int e = blockIdx.x * 256 + threadIdx.x;
  if (e < NE) { int d = dst[e]; int p = atomicAdd(&nxt[d], 1); esp[p] = src[e]; enp[p] = en[e]; }
}

// ---------------- weight convert/transpose: Wt[n*K+k] = bf16(W[k*N+n]) ----------------
__global__ void k_cvt_wT(const float* __restrict__ W, unsigned short* __restrict__ Wt, int K, int N) {
  int id = blockIdx.x * 256 + threadIdx.x;
  if (id >= K * N) return;
  int n = id / K, k = id - n * K;
  Wt[id] = f2bf(W[k * N + n]);
}

// ---------------- layer-1 GEMM: x[NN,16] fp32 @ W1 -> bf16 ----------------
__global__ __launch_bounds__(256) void k_gemm16(const float* __restrict__ x, const float* __restrict__ W,
                                                unsigned short* __restrict__ out) {
  __shared__ float xs[32][16];
  int t = threadIdx.x; int row0 = blockIdx.x * 32;
  for (int i = t; i < 512; i += 256) {
    int r = i >> 4, c = i & 15; int row = row0 + r;
    xs[r][c] = (row < NN) ? x[(size_t)row * 16 + c] : 0.f;
  }
  float w[16];
  #pragma unroll
  for (int k = 0; k < 16; k++) w[k] = W[k * 256 + t];
  __syncthreads();
  for (int r = 0; r < 32; r++) {
    int row = row0 + r; if (row >= NN) break;
    float acc = 0.f;
    #pragma unroll
    for (int k = 0; k < 16; k++) acc += xs[r][k] * w[k];
    out[(size_t)row * 256 + t] = f2bf(acc);
  }
}

// ---------------- MFMA GEMM with fused BN+ReLU on A ----------------
// A [NN][256] bf16 (pre-BN), Wt [FOUT][256] bf16, C [NN][FOUT] bf16
template <int FOUT>
__global__ __launch_bounds__(256) void k_gemm_mfma(
    const unsigned short* __restrict__ A, const unsigned short* __restrict__ Wt,
    const float* __restrict__ scale, const float* __restrict__ shift,
    unsigned short* __restrict__ C) {
  __shared__ unsigned short S[128 * 264];
  __shared__ float sc[256], sh[256];
  const int t = threadIdx.x;
  const int row0 = blockIdx.x * 128;
  sc[t] = scale[t]; sh[t] = shift[t];
  __syncthreads();
  // stage A tile with BN+ReLU applied, bf16 -> LDS
  {
    int r = t >> 1, hh = t & 1;
    int row = row0 + r;
    const uint4* src = (const uint4*)(A + (size_t)row * 256 + hh * 128);
    uint4* dst = (uint4*)(S + r * 264 + hh * 128);
    int kb = hh * 128;
    #pragma unroll
    for (int i = 0; i < 16; i++) {
      uint4 v = (row < NN) ? src[i] : make_uint4(0, 0, 0, 0);
      unsigned int wo[4];
      unsigned int in[4] = {v.x, v.y, v.z, v.w};
      #pragma unroll
      for (int p = 0; p < 4; p++) {
        int k = kb + i * 8 + p * 2;
        float lo = bf2f((unsigned short)(in[p] & 0xFFFF)) * sc[k] + sh[k];
        float hi = bf2f((unsigned short)(in[p] >> 16)) * sc[k + 1] + sh[k + 1];
        lo = fmaxf(lo, 0.f); hi = fmaxf(hi, 0.f);
        wo[p] = (unsigned int)f2bf(lo) | ((unsigned int)f2bf(hi) << 16);
      }
      dst[i] = make_uint4(wo[0], wo[1], wo[2], wo[3]);
    }
  }
  __syncthreads();
  const int lane = t & 63, w = t >> 6, fr = lane & 15, fq = lane >> 4;
  f32x4 acc[2][FOUT / 16] = {};
  #pragma unroll
  for (int s = 0; s < 8; s++) {
    bf16x8 a0 = *(const bf16x8*)(S + (w * 32 + fr) * 264 + s * 32 + fq * 8);
    bf16x8 a1 = *(const bf16x8*)(S + (w * 32 + 16 + fr) * 264 + s * 32 + fq * 8);
    #pragma unroll
    for (int j = 0; j < FOUT / 16; j++) {
      bf16x8 bw = *(const bf16x8*)(Wt + (size_t)(j * 16 + fr) * 256 + s * 32 + fq * 8);
      acc[0][j] = __builtin_amdgcn_mfma_f32_16x16x32_bf16(a0, bw, acc[0][j], 0, 0, 0);
      acc[1][j] = __builtin_amdgcn_mfma_f32_16x16x32_bf16(a1, bw, acc[1][j], 0, 0, 0);
    }
  }
  #pragma unroll
  for (int f = 0; f < 2; f++)
    #pragma unroll
    for (int j = 0; j < FOUT / 16; j++)
      #pragma unroll
      for (int rr = 0; rr < 4; rr++) {
        int orow = row0 + w * 32 + f * 16 + fq * 4 + rr;
        if (orow < NN) C[(size_t)orow * FOUT + j * 16 + fr] = f2bf(acc[f][j][rr]);
      }
}

// ---------------- aggregation (CSR gather, bf16 in/out, fp32 accum) ----------------
template <int FPL>
__device__ __forceinline__ void ldbf(const unsigned short* p, float* f) {
  if constexpr (FPL == 4) {
    ushort4 v = *(const ushort4*)p;
    f[0] = bf2f(v.x); f[1] = bf2f(v.y); f[2] = bf2f(v.z); f[3] = bf2f(v.w);
  } else {
    ushort2 v = *(const ushort2*)p;
    f[0] = bf2f(v.x); f[1] = bf2f(v.y);
  }
}
template <int F>
__global__ __launch_bounds__(256) void k_agg2(const unsigned short* __restrict__ hb,
    const int* __restrict__ esp, const float* __restrict__ enp,
    const int* __restrict__ rowptr, const float* __restrict__ dinv,
    const float* __restrict__ bias, unsigned short* __restrict__ outb) {
  constexpr int FPL = F / 64;
  const int lane = threadIdx.x & 63;
  const int n = blockIdx.x * 4 + (threadIdx.x >> 6);
  const int f0 = lane * FPL;
  float d = dinv[n]; float dd = d * d;
  float acc[FPL];
  {
    float sv[FPL];
    ldbf<FPL>(hb + (size_t)n * F + f0, sv);
    #pragma unroll
    for (int j = 0; j < FPL; j++) acc[j] = sv[j] * dd + bias[f0 + j];
  }
  int i = rowptr[n], i1 = rowptr[n + 1];
  for (; i + 2 <= i1; i += 2) {
    int s0 = esp[i], s1 = esp[i + 1];
    float w0 = enp[i], w1 = enp[i + 1];
    float r0[FPL], r1[FPL];
    ldbf<FPL>(hb + (size_t)s0 * F + f0, r0);
    ldbf<FPL>(hb + (size_t)s1 * F + f0, r1);
    #pragma unroll
    for (int j = 0; j < FPL; j++) acc[j] += w0 * r0[j] + w1 * r1[j];
  }
  if (i < i1) {
    int s0 = esp[i]; float w0 = enp[i];
    float r0[FPL];
    ldbf<FPL>(hb + (size_t)s0 * F + f0, r0);
    #pragma unroll
    for (int j = 0; j < FPL; j++) acc[j] += w0 * r0[j];
  }
  if constexpr (FPL == 4) {
    ushort4 o; o.x = f2bf(acc[0]); o.y = f2bf(acc[1]); o.z = f2bf(acc[2]); o.w = f2bf(acc[3]);
    *(ushort4*)(outb + (size_t)n * F + f0) = o;
  } else {
    ushort2 o; o.x = f2bf(acc[0]); o.y = f2bf(acc[1]);
    *(ushort2*)(outb + (size_t)n * F + f0) = o;
  }
}

// ---------------- batchnorm stats (bf16 input) ----------------
__global__ __launch_bounds__(256) void k_bnstats2(const unsigned short* __restrict__ h,
                                                  float* __restrict__ sums, float* __restrict__ sqs) {
  __shared__ float L[4][256];
  int t = threadIdx.x;
  int fp = t & 127;
  size_t rbase = (size_t)blockIdx.x * 256 + (t >> 7);
  float s0 = 0, q0 = 0, s1 = 0, q1 = 0;
  for (int i = 0; i < 128; i++) {
    size_t r = rbase + 2 * (size_t)i;
    if (r >= NN) break;
    unsigned int v = *(const unsigned int*)&h[r * 256 + fp * 2];
    float a = bf2f((unsigned short)(v & 0xFFFF));
    float b = bf2f((unsigned short)(v >> 16));
    s0 += a; q0 += a * a; s1 += b; q1 += b * b;
  }
  L[0][t] = s0; L[1][t] = q0; L[2][t] = s1; L[3][t] = q1;
  __syncthreads();
  if (t < 128) {
    s0 = L[0][t] + L[0][t + 128]; q0 = L[1][t] + L[1][t + 128];
    s1 = L[2][t] + L[2][t + 128]; q1 = L[3][t] + L[3][t + 128];
    atomicAdd(&sums[2 * t], s0); atomicAdd(&sqs[2 * t], q0);
    atomicAdd(&sums[2 * t + 1], s1); atomicAdd(&sqs[2 * t + 1], q1);
  }
}
__global__ void k_bnfinal(const float* __restrict__ sums, const float* __restrict__ sqs,
                          const float* __restrict__ g, const float* __restrict__ be,
                          float* __restrict__ scale, float* __restrict__ shift) {
  int f = threadIdx.x;
  float m = sums[f] * (1.f / NN);
  float v = sqs[f] * (1.f / NN) - m * m;
  float sc = g[f] * rsqrtf(v + 1e-5f);
  scale[f] = sc; shift[f] = be[f] - m * sc;
}

// ---------------- fused decoder (bf16 MFMA) ----------------
__global__ __launch_bounds__(256) void k_decoder2(
    const unsigned short* __restrict__ zbf, const int* __restrict__ l0, const int* __restrict__ l1,
    const unsigned short* __restrict__ W1t, const float* __restrict__ D1b,
    const unsigned short* __restrict__ W2t, const float* __restrict__ D2b,
    const float* __restrict__ D3W, const float* __restrict__ D3b,
    float* __restrict__ out) {
  __shared__ unsigned short S[128 * 264];
  __shared__ int ei0[128], ei1[128];
  const int t = threadIdx.x;
  const int base = blockIdx.x * 128;
  if (t < 128) ei0[t] = l0[base + t];
  else ei1[t - 128] = l1[base + t - 128];
  __syncthreads();
  {
    int e = t >> 1, h = t & 1;
    int node = h ? ei1[e] : ei0[e];
    const uint4* src = (const uint4*)(zbf + (size_t)node * 128);
    uint4* dst = (uint4*)(S + e * 264 + h * 128);
    #pragma unroll
    for (int i = 0; i < 16; i++) dst[i] = src[i];
  }
  __syncthreads();
  const int lane = t & 63, w = t >> 6, fr = lane & 15, fq = lane >> 4;
  float b1v[8];
  #pragma unroll
  for (int j = 0; j < 8; j++) b1v[j] = D1b[j * 16 + fr];
  f32x4 acc[2][8] = {};
  #pragma unroll
  for (int s = 0; s < 8; s++) {
    bf16x8 a0 = *(const bf16x8*)(S + (w * 32 + fr) * 264 + s * 32 + fq * 8);
    bf16x8 a1 = *(const bf16x8*)(S + (w * 32 + 16 + fr) * 264 + s * 32 + fq * 8);
    bf16x8 bw[8];
    #pragma unroll
    for (int j = 0; j < 8; j++)
      bw[j] = *(const bf16x8*)(W1t + (size_t)(j * 16 + fr) * 256 + s * 32 + fq * 8);
    #pragma unroll
    for (int j = 0; j < 8; j++) {
      acc[0][j] = __builtin_amdgcn_mfma_f32_16x16x32_bf16(a0, bw[j], acc[0][j], 0, 0, 0);
      acc[1][j] = __builtin_amdgcn_mfma_f32_16x16x32_bf16(a1, bw[j], acc[1][j], 0, 0, 0);
    }
  }
  __syncthreads();
  #pragma unroll
  for (int f = 0; f < 2; f++)
    #pragma unroll
    for (int j = 0; j < 8; j++)
      #pragma unroll
      for (int r = 0; r < 4; r++) {
        int row = w * 32 + f * 16 + fq * 4 + r;
        S[row * 136 + j * 16 + fr] = f2bf(fmaxf(acc[f][j][r] + b1v[j], 0.f));
      }
  __syncthreads();
  f32x4 acc2[2][8] = {};
  #pragma unroll
  for (int s = 0; s < 4; s++) {
    bf16x8 a0 = *(const bf16x8*)(S + (w * 32 + fr) * 136 + s * 32 + fq * 8);
    bf16x8 a1 = *(const bf16x8*)(S + (w * 32 + 16 + fr) * 136 + s * 32 + fq * 8);
    bf16x8 bw[8];
    #pragma unroll
    for (int j = 0; j < 8; j++)
      bw[j] = *(const bf16x8*)(W2t + (size_t)(j * 16 + fr) * 128 + s * 32 + fq * 8);
    #pragma unroll
    for (int j = 0; j < 8; j++) {
      acc2[0][j] = __builtin_amdgcn_mfma_f32_16x16x32_bf16(a0, bw[j], acc2[0][j], 0, 0, 0);
      acc2[1][j] = __builtin_amdgcn_mfma_f32_16x16x32_bf16(a1, bw[j], acc2[1][j], 0, 0, 0);
    }
  }
  float b2v[8], w3v[8];
  #pragma unroll
  for (int j = 0; j < 8; j++) { b2v[j] = D2b[j * 16 + fr]; w3v[j] = D3W[j * 16 + fr]; }
  float d3b = D3b[0];
  #pragma unroll
  for (int f = 0; f < 2; f++) {
    float p[4] = {0.f, 0.f, 0.f, 0.f};
    #pragma unroll
    for (int j = 0; j < 8; j++)
      #pragma unroll
      for (int r = 0; r < 4; r++)
        p[r] += fmaxf(acc2[f][j][r] + b2v[j], 0.f) * w3v[j];
    #pragma unroll
    for (int r = 0; r < 4; r++) {
      p[r] += __shfl_xor(p[r], 1);
      p[r] += __shfl_xor(p[r], 2);
      p[r] += __shfl_xor(p[r], 4);
      p[r] += __shfl_xor(p[r], 8);
      if (fr == 0) out[base + w * 32 + f * 16 + fq * 4 + r] = 1.f / (1.f + expf(-(p[r] + d3b)));
    }
  }
}

// ---------------- host ----------------
extern "C" void kernel_launch(void* const* d_in, const int* in_sizes, int n_in,
                              void* d_out, int out_size, void* d_ws, size_t ws_size,
                              hipStream_t stream) {
  const float* x = (const float*)d_in[0];
  const int* ei = (const int*)d_in[1];
  const int* esrc = ei; const int* edst = ei + NE;
  const float* ew = (const float*)d_in[2];
  const int* eli = (const int*)d_in[3];
  const int* l0 = eli; const int* l1 = eli + NL;
  const float* W1 = (const float*)d_in[4],  *b1 = (const float*)d_in[5];
  const float* g1 = (const float*)d_in[6],  *be1 = (const float*)d_in[7];
  const float* W2 = (const float*)d_in[8],  *b2 = (const float*)d_in[9];
  const float* g2 = (const float*)d_in[10], *be2 = (const float*)d_in[11];
  const float* W3 = (const float*)d_in[12], *b3 = (const float*)d_in[13];
  const float* g3 = (const float*)d_in[14], *be3 = (const float*)d_in[15];
  const float* W4 = (const float*)d_in[16], *b4 = (const float*)d_in[17];
  const float* D1W = (const float*)d_in[18], *D1b = (const float*)d_in[19];
  const float* D2W = (const float*)d_in[20], *D2b = (const float*)d_in[21];
  const float* D3W = (const float*)d_in[22], *D3b = (const float*)d_in[23];
  float* out = (float*)d_out;

  float* wf = (float*)d_ws;
  size_t off = 0;
  auto A = [&](size_t n) { float* p = wf + off; off += (n + 63) & ~(size_t)63; return p; };
  float* dinv = A(NN);
  float* en = A(NE);
  float* enp = A(NE);
  float* sums = A(256);
  float* sqs = A(256);
  float* scale = A(256);
  float* shift = A(256);
  int* cnt = (int*)A(NN);
  int* rowptr = (int*)A(NN + 1);
  int* nxt = (int*)A(NN);
  int* esp = (int*)A(NE);
  int* tsum = (int*)A(256);
  int* toff = (int*)A(256);
  unsigned short* hb0 = (unsigned short*)A((size_t)NN * 128);   // NN*256 ushorts
  unsigned short* hb1 = (unsigned short*)A((size_t)NN * 128);
  unsigned short* zbf = (unsigned short*)A((size_t)NN * 64);    // NN*128 ushorts
  unsigned short* wt2 = (unsigned short*)A(256 * 128);          // [256][256] bf16
  unsigned short* wt3 = (unsigned short*)A(256 * 128);
  unsigned short* wt4 = (unsigned short*)A(128 * 128);          // [128][256]
  unsigned short* w1t = (unsigned short*)A(128 * 128);          // [128][256]
  unsigned short* w2t = (unsigned short*)A(64 * 128);           // [128][128]

  const int EB = (NE + 255) / 256;
  const int NB = (NN + 255) / 256;
  const int ST = (NN + 1023) / 1024;
  const int GB = (NN + 127) / 128;       // gemm blocks
  const int AB = NN / 4;                  // agg blocks (NN divisible by 4)

  // graph prep
  hipMemsetAsync(dinv, 0, NN * sizeof(float), stream);
  hipMemsetAsync(cnt, 0, NN * sizeof(int), stream);
  k_deg<<<EB, 256, 0, stream>>>(edst, ew, dinv);
  k_dinv<<<NB, 256, 0, stream>>>(dinv);
  k_enorm<<<EB, 256, 0, stream>>>(esrc, edst, ew, dinv, en);
  k_count<<<EB, 256, 0, stream>>>(edst, cnt);
  k_scan1<<<ST, 256, 0, stream>>>(cnt, tsum);
  k_scan2<<<1, 256, 0, stream>>>(tsum, toff, ST, rowptr + NN);
  k_scan3<<<ST, 256, 0, stream>>>(cnt, toff, rowptr);
  k_copyi<<<NB, 256, 0, stream>>>(rowptr, nxt, NN);
  k_scatter<<<EB, 256, 0, stream>>>(esrc, edst, en, nxt, esp, enp);

  // weight conversions (bf16, transposed to [N][K])
  k_cvt_wT<<<(256 * 256 + 255) / 256, 256, 0, stream>>>(W2, wt2, 256, 256);
  k_cvt_wT<<<(256 * 256 + 255) / 256, 256, 0, stream>>>(W3, wt3, 256, 256);
  k_cvt_wT<<<(256 * 128 + 255) / 256, 256, 0, stream>>>(W4, wt4, 256, 128);
  k_cvt_wT<<<(256 * 128 + 255) / 256, 256, 0, stream>>>(D1W, w1t, 256, 128);
  k_cvt_wT<<<(128 * 128 + 255) / 256, 256, 0, stream>>>(D2W, w2t, 128, 128);

  // layer 1
  k_gemm16<<<(NN + 31) / 32, 256, 0, stream>>>(x, W1, hb0);
  k_agg2<256><<<AB, 256, 0, stream>>>(hb0, esp, enp, rowptr, dinv, b1, hb1);
  hipMemsetAsync(sums, 0, 512 * sizeof(float), stream);
  k_bnstats2<<<NB, 256, 0, stream>>>(hb1, sums, sqs);
  k_bnfinal<<<1, 256, 0, stream>>>(sums, sqs, g1, be1, scale, shift);
  // layer 2 (BN1+relu fused into A-stage)
  k_gemm_mfma<256><<<GB, 256, 0, stream>>>(hb1, wt2, scale, shift, hb0);
  k_agg2<256><<<AB, 256, 0, stream>>>(hb0, esp, enp, rowptr, dinv, b2, hb1);
  hipMemsetAsync(sums, 0, 512 * sizeof(float), stream);
  k_bnstats2<<<NB, 256, 0, stream>>>(hb1, sums, sqs);
  k_bnfinal<<<1, 256, 0, stream>>>(sums, sqs, g2, be2, scale, shift);
  // layer 3
  k_gemm_mfma<256><<<GB, 256, 0, stream>>>(hb1, wt3, scale, shift, hb0);
  k_agg2<256><<<AB, 256, 0, stream>>>(hb0, esp, enp, rowptr, dinv, b3, hb1);
  hipMemsetAsync(sums, 0, 512 * sizeof(float), stream);
  k_bnstats2<<<NB, 256, 0, stream>>>(hb1, sums, sqs);
  k_bnfinal<<<1, 256, 0, stream>>>(sums, sqs, g3, be3, scale, shift);
  // layer 4 (BN3+relu fused; no BN after)
  k_gemm_mfma<128><<<GB, 256, 0, stream>>>(hb1, wt4, scale, shift, hb0);
  k_agg2<128><<<AB, 256, 0, stream>>>(hb0, esp, enp, rowptr, dinv, b4, zbf);

  // decoder
  k_decoder2<<<NL / 128, 256, 0, stream>>>(zbf, l0, l1, w1t, D1b, w2t, D2b, D3W, D3b, out);
}

// Round 4
// 961.475 us; speedup vs baseline: 2.4295x; 1.0214x over previous
//
#include <hip/hip_runtime.h>
#include <cmath>

#define NN 100000
#define NE 800000
#define NL 262144

typedef __attribute__((ext_vector_type(8))) short bf16x8;
typedef __attribute__((ext_vector_type(4))) float f32x4;

__device__ __forceinline__ unsigned short f2bf(float f) {
  unsigned int u = __builtin_bit_cast(unsigned int, f);
  u = (u + 0x7FFF + ((u >> 16) & 1)) >> 16;
  return (unsigned short)u;
}
__device__ __forceinline__ float bf2f(unsigned short u) {
  return __builtin_bit_cast(float, (unsigned int)u << 16);
}

// ---------------- graph prep ----------------
__global__ void k_deg(const int* __restrict__ dst, const float* __restrict__ w, float* __restrict__ deg) {
  int e = blockIdx.x * 256 + threadIdx.x;
  if (e < NE) atomicAdd(&deg[dst[e]], w[e]);
}
__global__ void k_dinv(float* __restrict__ deg) {
  int n = blockIdx.x * 256 + threadIdx.x;
  if (n < NN) deg[n] = rsqrtf(deg[n] + 1.0f);
}
__global__ void k_enorm(const int* __restrict__ src, const int* __restrict__ dst, const float* __restrict__ w,
                        const float* __restrict__ dinv, float* __restrict__ en) {
  int e = blockIdx.x * 256 + threadIdx.x;
  if (e < NE) en[e] = dinv[src[e]] * w[e] * dinv[dst[e]];
}
__global__ void k_count(const int* __restrict__ dst, int* __restrict__ cnt) {
  int e = blockIdx.x * 256 + threadIdx.x;
  if (e < NE) atomicAdd(&cnt[dst[e]], 1);
}
__global__ void k_scan1(const int* __restrict__ cnt, int* __restrict__ tsum) {
  __shared__ int s[256];
  int t = threadIdx.x;
  int base = blockIdx.x * 1024;
  int acc = 0;
  for (int i = 0; i < 4; i++) { int idx = base + t * 4 + i; if (idx < NN) acc += cnt[idx]; }
  s[t] = acc; __syncthreads();
  for (int o = 128; o > 0; o >>= 1) { if (t < o) s[t] += s[t + o]; __syncthreads(); }
  if (t == 0) tsum[blockIdx.x] = s[0];
}
__global__ void k_scan2(const int* __restrict__ tsum, int* __restrict__ toff, int nt, int* __restrict__ rowptr_end) {
  __shared__ int s[256];
  int t = threadIdx.x;
  int v = (t < nt) ? tsum[t] : 0;
  s[t] = v; __syncthreads();
  for (int o = 1; o < 256; o <<= 1) { int xv = (t >= o) ? s[t - o] : 0; __syncthreads(); s[t] += xv; __syncthreads(); }
  if (t < nt) toff[t] = s[t] - v;
  if (t == 255) *rowptr_end = s[255];
}
__global__ void k_scan3(const int* __restrict__ cnt, const int* __restrict__ toff, int* __restrict__ rowptr) {
  __shared__ int s[256];
  int t = threadIdx.x;
  int base = blockIdx.x * 1024 + t * 4;
  int v[4]; int tot = 0;
  for (int i = 0; i < 4; i++) { int idx = base + i; v[i] = (idx < NN) ? cnt[idx] : 0; tot += v[i]; }
  s[t] = tot; __syncthreads();
  for (int o = 1; o < 256; o <<= 1) { int xv = (t >= o) ? s[t - o] : 0; __syncthreads(); s[t] += xv; __syncthreads(); }
  int excl = s[t] - tot + toff[blockIdx.x];
  for (int i = 0; i < 4; i++) { int idx = base + i; if (idx < NN) rowptr[idx] = excl; excl += v[i]; }
}
__global__ void k_copyi(const int* __restrict__ a, int* __restrict__ b, int n) {
  int i = blockIdx.x * 256 + threadIdx.x; if (i < n) b[i] = a[i];
}
__global__ void k_scatter(const int* __restrict__ src, const int* __restrict__ dst, const float* __restrict__ en,
                          int* __restrict__ nxt, int* __restrict__ esp, float* __restrict__ enp) {
  int e = blockIdx.x * 256 + threadIdx.x;
  if (e < NE) { int d = dst[e]; int p = atomicAdd(&nxt[d], 1); esp[p] = src[e]; enp[p] = en[e]; }
}

// ---------------- weight convert/transpose: Wt[n*K+k] = bf16(W[k*N+n]) ----------------
__global__ void k_cvt_wT(const float* __restrict__ W, unsigned short* __restrict__ Wt, int K, int N) {
  int id = blockIdx.x * 256 + threadIdx.x;
  if (id >= K * N) return;
  int n = id / K, k = id - n * K;
  Wt[id] = f2bf(W[k * N + n]);
}

// ---------------- layer-1 GEMM: x[NN,16] fp32 @ W1 -> bf16 ----------------
__global__ __launch_bounds__(256) void k_gemm16(const float* __restrict__ x, const float* __restrict__ W,
                                                unsigned short* __restrict__ out) {
  __shared__ float xs[32][16];
  int t = threadIdx.x; int row0 = blockIdx.x * 32;
  for (int i = t; i < 512; i += 256) {
    int r = i >> 4, c = i & 15; int row = row0 + r;
    xs[r][c] = (row < NN) ? x[(size_t)row * 16 + c] : 0.f;
  }
  float w[16];
  #pragma unroll
  for (int k = 0; k < 16; k++) w[k] = W[k * 256 + t];
  __syncthreads();
  for (int r = 0; r < 32; r++) {
    int row = row0 + r; if (row >= NN) break;
    float acc = 0.f;
    #pragma unroll
    for (int k = 0; k < 16; k++) acc += xs[r][k] * w[k];
    out[(size_t)row * 256 + t] = f2bf(acc);
  }
}

// ---------------- MFMA GEMM with fused BN+ReLU on A ----------------
template <int FOUT>
__global__ __launch_bounds__(256) void k_gemm_mfma(
    const unsigned short* __restrict__ A, const unsigned short* __restrict__ Wt,
    const float* __restrict__ scale, const float* __restrict__ shift,
    unsigned short* __restrict__ C) {
  __shared__ unsigned short S[128 * 264];
  __shared__ float sc[256], sh[256];
  const int t = threadIdx.x;
  const int row0 = blockIdx.x * 128;
  sc[t] = scale[t]; sh[t] = shift[t];
  __syncthreads();
  {
    int r = t >> 1, hh = t & 1;
    int row = row0 + r;
    const uint4* src = (const uint4*)(A + (size_t)row * 256 + hh * 128);
    uint4* dst = (uint4*)(S + r * 264 + hh * 128);
    int kb = hh * 128;
    #pragma unroll
    for (int i = 0; i < 16; i++) {
      uint4 v = (row < NN) ? src[i] : make_uint4(0, 0, 0, 0);
      unsigned int wo[4];
      unsigned int in[4] = {v.x, v.y, v.z, v.w};
      #pragma unroll
      for (int p = 0; p < 4; p++) {
        int k = kb + i * 8 + p * 2;
        float lo = bf2f((unsigned short)(in[p] & 0xFFFF)) * sc[k] + sh[k];
        float hi = bf2f((unsigned short)(in[p] >> 16)) * sc[k + 1] + sh[k + 1];
        lo = fmaxf(lo, 0.f); hi = fmaxf(hi, 0.f);
        wo[p] = (unsigned int)f2bf(lo) | ((unsigned int)f2bf(hi) << 16);
      }
      dst[i] = make_uint4(wo[0], wo[1], wo[2], wo[3]);
    }
  }
  __syncthreads();
  const int lane = t & 63, w = t >> 6, fr = lane & 15, fq = lane >> 4;
  f32x4 acc[2][FOUT / 16] = {};
  #pragma unroll
  for (int s = 0; s < 8; s++) {
    bf16x8 a0 = *(const bf16x8*)(S + (w * 32 + fr) * 264 + s * 32 + fq * 8);
    bf16x8 a1 = *(const bf16x8*)(S + (w * 32 + 16 + fr) * 264 + s * 32 + fq * 8);
    #pragma unroll
    for (int j = 0; j < FOUT / 16; j++) {
      bf16x8 bw = *(const bf16x8*)(Wt + (size_t)(j * 16 + fr) * 256 + s * 32 + fq * 8);
      acc[0][j] = __builtin_amdgcn_mfma_f32_16x16x32_bf16(a0, bw, acc[0][j], 0, 0, 0);
      acc[1][j] = __builtin_amdgcn_mfma_f32_16x16x32_bf16(a1, bw, acc[1][j], 0, 0, 0);
    }
  }
  #pragma unroll
  for (int f = 0; f < 2; f++)
    #pragma unroll
    for (int j = 0; j < FOUT / 16; j++)
      #pragma unroll
      for (int rr = 0; rr < 4; rr++) {
        int orow = row0 + w * 32 + f * 16 + fq * 4 + rr;
        if (orow < NN) C[(size_t)orow * FOUT + j * 16 + fr] = f2bf(acc[f][j][rr]);
      }
}

// ---------------- u/v precompute for decoder layer 1 ----------------
// u[n] = z[n] @ D1W[0:128,:] + D1b ; v[n] = z[n] @ D1W[128:256,:]
// w1t layout: [128 out][256 in] bf16
__global__ __launch_bounds__(256) void k_uv(
    const unsigned short* __restrict__ zbf, const unsigned short* __restrict__ w1t,
    const float* __restrict__ D1b,
    unsigned short* __restrict__ ub, unsigned short* __restrict__ vb) {
  __shared__ unsigned short S[128 * 136];
  const int t = threadIdx.x;
  const int row0 = blockIdx.x * 128;
  {
    int r = t >> 1, h = t & 1;
    int row = row0 + r;
    uint4* dst = (uint4*)(S + r * 136 + h * 64);
    if (row < NN) {
      const uint4* src = (const uint4*)(zbf + (size_t)row * 128 + h * 64);
      #pragma unroll
      for (int i = 0; i < 8; i++) dst[i] = src[i];
    } else {
      #pragma unroll
      for (int i = 0; i < 8; i++) dst[i] = make_uint4(0, 0, 0, 0);
    }
  }
  __syncthreads();
  const int lane = t & 63, w = t >> 6, fr = lane & 15, fq = lane >> 4;
  f32x4 au[2][8] = {}, av[2][8] = {};
  #pragma unroll
  for (int s = 0; s < 4; s++) {
    bf16x8 a0 = *(const bf16x8*)(S + (w * 32 + fr) * 136 + s * 32 + fq * 8);
    bf16x8 a1 = *(const bf16x8*)(S + (w * 32 + 16 + fr) * 136 + s * 32 + fq * 8);
    #pragma unroll
    for (int j = 0; j < 8; j++) {
      bf16x8 bu = *(const bf16x8*)(w1t + (size_t)(j * 16 + fr) * 256 + s * 32 + fq * 8);
      bf16x8 bv = *(const bf16x8*)(w1t + (size_t)(j * 16 + fr) * 256 + 128 + s * 32 + fq * 8);
      au[0][j] = __builtin_amdgcn_mfma_f32_16x16x32_bf16(a0, bu, au[0][j], 0, 0, 0);
      au[1][j] = __builtin_amdgcn_mfma_f32_16x16x32_bf16(a1, bu, au[1][j], 0, 0, 0);
      av[0][j] = __builtin_amdgcn_mfma_f32_16x16x32_bf16(a0, bv, av[0][j], 0, 0, 0);
      av[1][j] = __builtin_amdgcn_mfma_f32_16x16x32_bf16(a1, bv, av[1][j], 0, 0, 0);
    }
  }
  #pragma unroll
  for (int f = 0; f < 2; f++)
    #pragma unroll
    for (int j = 0; j < 8; j++) {
      float bj = D1b[j * 16 + fr];
      #pragma unroll
      for (int rr = 0; rr < 4; rr++) {
        int orow = row0 + w * 32 + f * 16 + fq * 4 + rr;
        if (orow < NN) {
          ub[(size_t)orow * 128 + j * 16 + fr] = f2bf(au[f][j][rr] + bj);
          vb[(size_t)orow * 128 + j * 16 + fr] = f2bf(av[f][j][rr]);
        }
      }
    }
}

// ---------------- aggregation (CSR gather, reg-prefetched edge meta) ----------------
template <int FPL>
__device__ __forceinline__ void ldbf(const unsigned short* p, float* f) {
  if constexpr (FPL == 4) {
    ushort4 v = *(const ushort4*)p;
    f[0] = bf2f(v.x); f[1] = bf2f(v.y); f[2] = bf2f(v.z); f[3] = bf2f(v.w);
  } else {
    ushort2 v = *(const ushort2*)p;
    f[0] = bf2f(v.x); f[1] = bf2f(v.y);
  }
}
template <int F>
__global__ __launch_bounds__(256) void k_agg3(const unsigned short* __restrict__ hb,
    const int* __restrict__ esp, const float* __restrict__ enp,
    const int* __restrict__ rowptr, const float* __restrict__ dinv,
    const float* __restrict__ bias, unsigned short* __restrict__ outb) {
  constexpr int FPL = F / 64;
  const int lane = threadIdx.x & 63;
  const int n = blockIdx.x * 4 + (threadIdx.x >> 6);
  const int f0 = lane * FPL;
  float d = dinv[n]; float dd = d * d;
  float acc[FPL];
  {
    float sv[FPL];
    ldbf<FPL>(hb + (size_t)n * F + f0, sv);
    #pragma unroll
    for (int j = 0; j < FPL; j++) acc[j] = sv[j] * dd + bias[f0 + j];
  }
  const int i0 = rowptr[n];
  const int dg = rowptr[n + 1] - i0;
  // prefetch edge meta into registers (lane-parallel), broadcast via shfl
  int sreg = 0; float wreg = 0.f;
  if (lane < dg) { sreg = esp[i0 + lane]; wreg = enp[i0 + lane]; }
  const int m = (dg < 64) ? dg : 64;
  int e = 0;
  for (; e + 4 <= m; e += 4) {
    int s0 = __shfl(sreg, e), s1 = __shfl(sreg, e + 1), s2 = __shfl(sreg, e + 2), s3 = __shfl(sreg, e + 3);
    float w0 = __shfl(wreg, e), w1 = __shfl(wreg, e + 1), w2 = __shfl(wreg, e + 2), w3 = __shfl(wreg, e + 3);
    float r0[FPL], r1[FPL], r2[FPL], r3[FPL];
    ldbf<FPL>(hb + (size_t)s0 * F + f0, r0);
    ldbf<FPL>(hb + (size_t)s1 * F + f0, r1);
    ldbf<FPL>(hb + (size_t)s2 * F + f0, r2);
    ldbf<FPL>(hb + (size_t)s3 * F + f0, r3);
    #pragma unroll
    for (int j = 0; j < FPL; j++) acc[j] += w0 * r0[j] + w1 * r1[j] + w2 * r2[j] + w3 * r3[j];
  }
  for (; e < m; e++) {
    int s0 = __shfl(sreg, e); float w0 = __shfl(wreg, e);
    float r0[FPL];
    ldbf<FPL>(hb + (size_t)s0 * F + f0, r0);
    #pragma unroll
    for (int j = 0; j < FPL; j++) acc[j] += w0 * r0[j];
  }
  for (int i = i0 + 64; i < i0 + dg; i++) {  // degree > 64 fallback (rare)
    int s0 = esp[i]; float w0 = enp[i];
    float r0[FPL];
    ldbf<FPL>(hb + (size_t)s0 * F + f0, r0);
    #pragma unroll
    for (int j = 0; j < FPL; j++) acc[j] += w0 * r0[j];
  }
  if constexpr (FPL == 4) {
    ushort4 o; o.x = f2bf(acc[0]); o.y = f2bf(acc[1]); o.z = f2bf(acc[2]); o.w = f2bf(acc[3]);
    *(ushort4*)(outb + (size_t)n * F + f0) = o;
  } else {
    ushort2 o; o.x = f2bf(acc[0]); o.y = f2bf(acc[1]);
    *(ushort2*)(outb + (size_t)n * F + f0) = o;
  }
}

// ---------------- batchnorm stats (bf16 input) ----------------
__global__ __launch_bounds__(256) void k_bnstats2(const unsigned short* __restrict__ h,
                                                  float* __restrict__ sums, float* __restrict__ sqs) {
  __shared__ float L[4][256];
  int t = threadIdx.x;
  int fp = t & 127;
  size_t rbase = (size_t)blockIdx.x * 256 + (t >> 7);
  float s0 = 0, q0 = 0, s1 = 0, q1 = 0;
  for (int i = 0; i < 128; i++) {
    size_t r = rbase + 2 * (size_t)i;
    if (r >= NN) break;
    unsigned int v = *(const unsigned int*)&h[r * 256 + fp * 2];
    float a = bf2f((unsigned short)(v & 0xFFFF));
    float b = bf2f((unsigned short)(v >> 16));
    s0 += a; q0 += a * a; s1 += b; q1 += b * b;
  }
  L[0][t] = s0; L[1][t] = q0; L[2][t] = s1; L[3][t] = q1;
  __syncthreads();
  if (t < 128) {
    s0 = L[0][t] + L[0][t + 128]; q0 = L[1][t] + L[1][t + 128];
    s1 = L[2][t] + L[2][t + 128]; q1 = L[3][t] + L[3][t + 128];
    atomicAdd(&sums[2 * t], s0); atomicAdd(&sqs[2 * t], q0);
    atomicAdd(&sums[2 * t + 1], s1); atomicAdd(&sqs[2 * t + 1], q1);
  }
}
__global__ void k_bnfinal(const float* __restrict__ sums, const float* __restrict__ sqs,
                          const float* __restrict__ g, const float* __restrict__ be,
                          float* __restrict__ scale, float* __restrict__ shift) {
  int f = threadIdx.x;
  float m = sums[f] * (1.f / NN);
  float v = sqs[f] * (1.f / NN) - m * m;
  float sc = g[f] * rsqrtf(v + 1e-5f);
  scale[f] = sc; shift[f] = be[f] - m * sc;
}

// ---------------- fused decoder: q1 = relu(u[e0]+v[e1]); layers 2-3 ----------------
__global__ __launch_bounds__(256) void k_decoder3(
    const unsigned short* __restrict__ ub, const unsigned short* __restrict__ vb,
    const int* __restrict__ l0, const int* __restrict__ l1,
    const unsigned short* __restrict__ W2t, const float* __restrict__ D2b,
    const float* __restrict__ D3W, const float* __restrict__ D3b,
    float* __restrict__ out) {
  __shared__ unsigned short S[128 * 136];
  __shared__ int ei0[128], ei1[128];
  const int t = threadIdx.x;
  const int base = blockIdx.x * 128;
  if (t < 128) ei0[t] = l0[base + t];
  else ei1[t - 128] = l1[base + t - 128];
  __syncthreads();
  {
    int e = t >> 1, h = t & 1;
    const uint4* pu = (const uint4*)(ub + (size_t)ei0[e] * 128 + h * 64);
    const uint4* pv = (const uint4*)(vb + (size_t)ei1[e] * 128 + h * 64);
    uint4* dst = (uint4*)(S + e * 136 + h * 64);
    #pragma unroll
    for (int i = 0; i < 8; i++) {
      uint4 a = pu[i], b = pv[i];
      unsigned int ia[4] = {a.x, a.y, a.z, a.w};
      unsigned int ib[4] = {b.x, b.y, b.z, b.w};
      unsigned int o[4];
      #pragma unroll
      for (int p = 0; p < 4; p++) {
        float lo = fmaxf(bf2f((unsigned short)(ia[p] & 0xFFFF)) + bf2f((unsigned short)(ib[p] & 0xFFFF)), 0.f);
        float hi = fmaxf(bf2f((unsigned short)(ia[p] >> 16)) + bf2f((unsigned short)(ib[p] >> 16)), 0.f);
        o[p] = (unsigned int)f2bf(lo) | ((unsigned int)f2bf(hi) << 16);
      }
      dst[i] = make_uint4(o[0], o[1], o[2], o[3]);
    }
  }
  __syncthreads();
  const int lane = t & 63, w = t >> 6, fr = lane & 15, fq = lane >> 4;
  f32x4 acc2[2][8] = {};
  #pragma unroll
  for (int s = 0; s < 4; s++) {
    bf16x8 a0 = *(const bf16x8*)(S + (w * 32 + fr) * 136 + s * 32 + fq * 8);
    bf16x8 a1 = *(const bf16x8*)(S + (w * 32 + 16 + fr) * 136 + s * 32 + fq * 8);
    #pragma unroll
    for (int j = 0; j < 8; j++) {
      bf16x8 bw = *(const bf16x8*)(W2t + (size_t)(j * 16 + fr) * 128 + s * 32 + fq * 8);
      acc2[0][j] = __builtin_amdgcn_mfma_f32_16x16x32_bf16(a0, bw, acc2[0][j], 0, 0, 0);
      acc2[1][j] = __builtin_amdgcn_mfma_f32_16x16x32_bf16(a1, bw, acc2[1][j], 0, 0, 0);
    }
  }
  float b2v[8], w3v[8];
  #pragma unroll
  for (int j = 0; j < 8; j++) { b2v[j] = D2b[j * 16 + fr]; w3v[j] = D3W[j * 16 + fr]; }
  float d3b = D3b[0];
  #pragma unroll
  for (int f = 0; f < 2; f++) {
    float p[4] = {0.f, 0.f, 0.f, 0.f};
    #pragma unroll
    for (int j = 0; j < 8; j++)
      #pragma unroll
      for (int r = 0; r < 4; r++)
        p[r] += fmaxf(acc2[f][j][r] + b2v[j], 0.f) * w3v[j];
    #pragma unroll
    for (int r = 0; r < 4; r++) {
      p[r] += __shfl_xor(p[r], 1);
      p[r] += __shfl_xor(p[r], 2);
      p[r] += __shfl_xor(p[r], 4);
      p[r] += __shfl_xor(p[r], 8);
      if (fr == 0) out[base + w * 32 + f * 16 + fq * 4 + r] = 1.f / (1.f + expf(-(p[r] + d3b)));
    }
  }
}

// ---------------- host ----------------
extern "C" void kernel_launch(void* const* d_in, const int* in_sizes, int n_in,
                              void* d_out, int out_size, void* d_ws, size_t ws_size,
                              hipStream_t stream) {
  const float* x = (const float*)d_in[0];
  const int* ei = (const int*)d_in[1];
  const int* esrc = ei; const int* edst = ei + NE;
  const float* ew = (const float*)d_in[2];
  const int* eli = (const int*)d_in[3];
  const int* l0 = eli; const int* l1 = eli + NL;
  const float* W1 = (const float*)d_in[4],  *b1 = (const float*)d_in[5];
  const float* g1 = (const float*)d_in[6],  *be1 = (const float*)d_in[7];
  const float* W2 = (const float*)d_in[8],  *b2 = (const float*)d_in[9];
  const float* g2 = (const float*)d_in[10], *be2 = (const float*)d_in[11];
  const float* W3 = (const float*)d_in[12], *b3 = (const float*)d_in[13];
  const float* g3 = (const float*)d_in[14], *be3 = (const float*)d_in[15];
  const float* W4 = (const float*)d_in[16], *b4 = (const float*)d_in[17];
  const float* D1W = (const float*)d_in[18], *D1b = (const float*)d_in[19];
  const float* D2W = (const float*)d_in[20], *D2b = (const float*)d_in[21];
  const float* D3W = (const float*)d_in[22], *D3b = (const float*)d_in[23];
  float* out = (float*)d_out;

  float* wf = (float*)d_ws;
  size_t off = 0;
  auto A = [&](size_t n) { float* p = wf + off; off += (n + 63) & ~(size_t)63; return p; };
  float* dinv = A(NN);
  float* en = A(NE);
  float* enp = A(NE);
  float* sums = A(256);
  float* sqs = A(256);
  float* scale = A(256);
  float* shift = A(256);
  int* cnt = (int*)A(NN);
  int* rowptr = (int*)A(NN + 1);
  int* nxt = (int*)A(NN);
  int* esp = (int*)A(NE);
  int* tsum = (int*)A(256);
  int* toff = (int*)A(256);
  unsigned short* hb0 = (unsigned short*)A((size_t)NN * 128);   // NN*256 ushorts
  unsigned short* hb1 = (unsigned short*)A((size_t)NN * 128);
  unsigned short* zbf = (unsigned short*)A((size_t)NN * 64);    // NN*128 ushorts
  unsigned short* ubf = (unsigned short*)A((size_t)NN * 64);
  unsigned short* vbf = (unsigned short*)A((size_t)NN * 64);
  unsigned short* wt2 = (unsigned short*)A(256 * 128);
  unsigned short* wt3 = (unsigned short*)A(256 * 128);
  unsigned short* wt4 = (unsigned short*)A(128 * 128);
  unsigned short* w1t = (unsigned short*)A(128 * 128);
  unsigned short* w2t = (unsigned short*)A(64 * 128);

  const int EB = (NE + 255) / 256;
  const int NB = (NN + 255) / 256;
  const int ST = (NN + 1023) / 1024;
  const int GB = (NN + 127) / 128;
  const int AB = NN / 4;

  // graph prep
  hipMemsetAsync(dinv, 0, NN * sizeof(float), stream);
  hipMemsetAsync(cnt, 0, NN * sizeof(int), stream);
  k_deg<<<EB, 256, 0, stream>>>(edst, ew, dinv);
  k_dinv<<<NB, 256, 0, stream>>>(dinv);
  k_enorm<<<EB, 256, 0, stream>>>(esrc, edst, ew, dinv, en);
  k_count<<<EB, 256, 0, stream>>>(edst, cnt);
  k_scan1<<<ST, 256, 0, stream>>>(cnt, tsum);
  k_scan2<<<1, 256, 0, stream>>>(tsum, toff, ST, rowptr + NN);
  k_scan3<<<ST, 256, 0, stream>>>(cnt, toff, rowptr);
  k_copyi<<<NB, 256, 0, stream>>>(rowptr, nxt, NN);
  k_scatter<<<EB, 256, 0, stream>>>(esrc, edst, en, nxt, esp, enp);

  // weight conversions (bf16, transposed to [N][K])
  k_cvt_wT<<<(256 * 256 + 255) / 256, 256, 0, stream>>>(W2, wt2, 256, 256);
  k_cvt_wT<<<(256 * 256 + 255) / 256, 256, 0, stream>>>(W3, wt3, 256, 256);
  k_cvt_wT<<<(256 * 128 + 255) / 256, 256, 0, stream>>>(W4, wt4, 256, 128);
  k_cvt_wT<<<(256 * 128 + 255) / 256, 256, 0, stream>>>(D1W, w1t, 256, 128);
  k_cvt_wT<<<(128 * 128 + 255) / 256, 256, 0, stream>>>(D2W, w2t, 128, 128);

  // layer 1
  k_gemm16<<<(NN + 31) / 32, 256, 0, stream>>>(x, W1, hb0);
  k_agg3<256><<<AB, 256, 0, stream>>>(hb0, esp, enp, rowptr, dinv, b1, hb1);
  hipMemsetAsync(sums, 0, 512 * sizeof(float), stream);
  k_bnstats2<<<NB, 256, 0, stream>>>(hb1, sums, sqs);
  k_bnfinal<<<1, 256, 0, stream>>>(sums, sqs, g1, be1, scale, shift);
  // layer 2
  k_gemm_mfma<256><<<GB, 256, 0, stream>>>(hb1, wt2, scale, shift, hb0);
  k_agg3<256><<<AB, 256, 0, stream>>>(hb0, esp, enp, rowptr, dinv, b2, hb1);
  hipMemsetAsync(sums, 0, 512 * sizeof(float), stream);
  k_bnstats2<<<NB, 256, 0, stream>>>(hb1, sums, sqs);
  k_bnfinal<<<1, 256, 0, stream>>>(sums, sqs, g2, be2, scale, shift);
  // layer 3
  k_gemm_mfma<256><<<GB, 256, 0, stream>>>(hb1, wt3, scale, shift, hb0);
  k_agg3<256><<<AB, 256, 0, stream>>>(hb0, esp, enp, rowptr, dinv, b3, hb1);
  hipMemsetAsync(sums, 0, 512 * sizeof(float), stream);
  k_bnstats2<<<NB, 256, 0, stream>>>(hb1, sums, sqs);
  k_bnfinal<<<1, 256, 0, stream>>>(sums, sqs, g3, be3, scale, shift);
  // layer 4
  k_gemm_mfma<128><<<GB, 256, 0, stream>>>(hb1, wt4, scale, shift, hb0);
  k_agg3<128><<<AB, 256, 0, stream>>>(hb0, esp, enp, rowptr, dinv, b4, zbf);

  // decoder: precompute u,v then fused edge MLP
  k_uv<<<GB, 256, 0, stream>>>(zbf, w1t, D1b, ubf, vbf);
  k_decoder3<<<NL / 128, 256, 0, stream>>>(ubf, vbf, l0, l1, w2t, D2b, D3W, D3b, out);
}